// Round 1
// baseline (3366.796 us; speedup 1.0000x reference)
//
#include <hip/hip_runtime.h>

// GRU bidirectional, B=4096 T=16 I=1024 H=1024, fp32 in/out, bf16 MFMA compute.
//
// Structure:
//   U[b*T+t, 0:3H]   = x[b,t,:] @ [W_izr; W_it]^T        (one big GEMM, bf16 out)
//   per step s (fwd processes x[s], bwd processes x[T-1-s], stacked M=2B):
//     Gh[m, 0:3H]    = h[m,:] @ [W_hzr; W_ht]^T           (GEMM, fp32 out)
//     gate kernel: r=sig(Ur+Ghr+b), z=sig(Uz+Ghz+b),
//                  h~=tanh(Ut+b_it + r*(Ght+b_ht)), h'=z*h~+(1-z)*h
//     writes d_out[b, 15-s, 0:H] (fwd) / d_out[b, s, H:2H] (bwd)
//
// Workspace layout (~668 MiB):
//   x_bf   bf16 [B*T, I]      134.2 MB
//   U      bf16 [B*T, 3H]     402.7 MB
//   Wi     bf16 [3H, I]         6.3 MB
//   Wh     bf16 [3H, H]         6.3 MB
//   h_bf   bf16 [2B, H]        16.8 MB
//   Gh     f32  [2B, 3H]      100.7 MB
//   h_f    f32  [2B, H]        33.6 MB

#define BDIM 4096
#define TDIM 16
#define IDIM 1024
#define HDIM 1024

typedef __bf16 bf16;
typedef __attribute__((ext_vector_type(8))) __bf16 bf16x8;
typedef __attribute__((ext_vector_type(4))) __bf16 bf16x4;
typedef __attribute__((ext_vector_type(4))) float f32x4;

__device__ __forceinline__ void g2l16(const bf16* g, bf16* l) {
  __builtin_amdgcn_global_load_lds(
      (const __attribute__((address_space(1))) void*)g,
      (__attribute__((address_space(3))) void*)l, 16, 0, 0);
}

__device__ __forceinline__ float sigmoidf_(float x) {
  return 1.0f / (1.0f + __expf(-x));
}
__device__ __forceinline__ float tanhfast_(float x) {
  // tanh(x) = 1 - 2/(exp(2x)+1); saturates correctly at +-inf
  return 1.0f - 2.0f / (__expf(2.0f * x) + 1.0f);
}

// C[M,N] = A[M,K] @ B[N,K]^T, bf16 inputs, fp32 accumulate, CT output.
// 128x128 tile, BK=64, global_load_lds(16B) staging, mfma_f32_16x16x32_bf16.
// Requires M%128==0, N%128==0, K%64==0. Grid: (N/128, M/128), block 256.
template <typename CT>
__global__ __launch_bounds__(256)
void gemm_bt(const bf16* __restrict__ A, const bf16* __restrict__ B,
             CT* __restrict__ C, int M, int N, int K)
{
  __shared__ bf16 sA[128 * 64];
  __shared__ bf16 sB[128 * 64];
  const int tid  = threadIdx.x;
  const int lane = tid & 63;
  const int wm = ((tid >> 6) >> 1) * 64;   // wave row offset (0/64)
  const int wn = ((tid >> 6) & 1) * 64;    // wave col offset (0/64)
  const long bm = (long)blockIdx.y * 128;
  const long bn = (long)blockIdx.x * 128;

  f32x4 acc[4][4] = {};

  // staging: linear idx = it*256+tid; row = idx>>3, col = (idx&7)*8 elems.
  // LDS dest = tile + idx*16B -> matches wave-uniform base + lane*16 rule.
  const int srow = tid >> 3;
  const int scol = (tid & 7) * 8;
  const bf16* Ab = A + bm * K;
  const bf16* Bb = B + bn * K;

  // MFMA fragment addressing (A and B identical: both [rows][K] in LDS)
  const int fm = lane & 15;         // row within 16
  const int fk = (lane >> 4) * 8;   // k offset within 32

  for (int k0 = 0; k0 < K; k0 += 64) {
    __syncthreads();   // prior iteration's LDS reads complete
#pragma unroll
    for (int it = 0; it < 4; ++it) {
      const int r = it * 32 + srow;
      g2l16(Ab + (long)r * K + k0 + scol, sA + (it * 256 + tid) * 8);
      g2l16(Bb + (long)r * K + k0 + scol, sB + (it * 256 + tid) * 8);
    }
    __syncthreads();   // staging complete (vmcnt drained before barrier)
#pragma unroll
    for (int kk = 0; kk < 2; ++kk) {
      bf16x8 af[4], bfr[4];
#pragma unroll
      for (int i = 0; i < 4; ++i) {
        af[i]  = *(const bf16x8*)(sA + (wm + i * 16 + fm) * 64 + kk * 32 + fk);
        bfr[i] = *(const bf16x8*)(sB + (wn + i * 16 + fm) * 64 + kk * 32 + fk);
      }
#pragma unroll
      for (int i = 0; i < 4; ++i)
#pragma unroll
        for (int j = 0; j < 4; ++j)
          acc[i][j] = __builtin_amdgcn_mfma_f32_16x16x32_bf16(
              af[i], bfr[j], acc[i][j], 0, 0, 0);
    }
  }

  // C/D layout: col = lane&15, row = (lane>>4)*4 + reg  [verified m89/m91]
  const int rg = (lane >> 4) * 4;
  const int cg = lane & 15;
#pragma unroll
  for (int i = 0; i < 4; ++i) {
#pragma unroll
    for (int j = 0; j < 4; ++j) {
      const long row0 = bm + wm + i * 16 + rg;
      const long col  = bn + wn + j * 16 + cg;
#pragma unroll
      for (int r = 0; r < 4; ++r) {
        C[(row0 + r) * (long)N + col] = (CT)acc[i][j][r];
      }
    }
  }
}

__global__ __launch_bounds__(256)
void conv_bf16(const float* __restrict__ src, bf16* __restrict__ dst, long n4) {
  long i = (long)blockIdx.x * blockDim.x + threadIdx.x;
  if (i >= n4) return;
  f32x4 v = *(const f32x4*)(src + i * 4);
  bf16x4 o;
  o[0] = (bf16)v[0]; o[1] = (bf16)v[1]; o[2] = (bf16)v[2]; o[3] = (bf16)v[3];
  *(bf16x4*)(dst + i * 4) = o;
}

__global__ __launch_bounds__(256)
void init_h(const float* __restrict__ h0, const float* __restrict__ bih0,
            float* __restrict__ hf, bf16* __restrict__ hb) {
  const long i4 = ((long)blockIdx.x * blockDim.x + threadIdx.x) * 4;
  const long nh = (long)BDIM * HDIM;
  const float* s = (i4 < nh) ? (h0 + i4) : (bih0 + (i4 - nh));
  f32x4 v = *(const f32x4*)s;
  *(f32x4*)(hf + i4) = v;
  bf16x4 o;
  o[0] = (bf16)v[0]; o[1] = (bf16)v[1]; o[2] = (bf16)v[2]; o[3] = (bf16)v[3];
  *(bf16x4*)(hb + i4) = o;
}

// grid = 2B blocks (one per (dir,b) row), 256 threads, 4 cols each.
__global__ __launch_bounds__(256)
void gate_step(const bf16* __restrict__ U, const float* __restrict__ Gh,
               float* __restrict__ hf, bf16* __restrict__ hb,
               const float* __restrict__ b_izr, const float* __restrict__ b_hzr,
               const float* __restrict__ b_it,  const float* __restrict__ b_ht,
               float* __restrict__ out, int s)
{
  const int m = blockIdx.x;             // 0..2B-1 (fwd rows then bwd rows)
  const int j = threadIdx.x * 4;        // 0..H-1
  const bool fwd = (m < BDIM);
  const int b  = fwd ? m : m - BDIM;
  const int tx = fwd ? s : (TDIM - 1 - s);   // x time index consumed this step
  const long urow = ((long)b * TDIM + tx) * (3 * HDIM);
  const long grow = (long)m * (3 * HDIM);
  const long hrow = (long)m * HDIM;

  bf16x4 ur = *(const bf16x4*)(U + urow + j);
  bf16x4 uz = *(const bf16x4*)(U + urow + HDIM + j);
  bf16x4 ut = *(const bf16x4*)(U + urow + 2 * HDIM + j);
  f32x4 gr = *(const f32x4*)(Gh + grow + j);
  f32x4 gz = *(const f32x4*)(Gh + grow + HDIM + j);
  f32x4 gt = *(const f32x4*)(Gh + grow + 2 * HDIM + j);
  f32x4 bri = *(const f32x4*)(b_izr + j);
  f32x4 bzi = *(const f32x4*)(b_izr + HDIM + j);
  f32x4 brh = *(const f32x4*)(b_hzr + j);
  f32x4 bzh = *(const f32x4*)(b_hzr + HDIM + j);
  f32x4 bti = *(const f32x4*)(b_it + j);
  f32x4 bth = *(const f32x4*)(b_ht + j);
  f32x4 hp = *(const f32x4*)(hf + hrow + j);

  f32x4 hn;
  bf16x4 hnb;
#pragma unroll
  for (int c = 0; c < 4; ++c) {
    float r = sigmoidf_((float)ur[c] + gr[c] + bri[c] + brh[c]);
    float z = sigmoidf_((float)uz[c] + gz[c] + bzi[c] + bzh[c]);
    float ht = tanhfast_((float)ut[c] + bti[c] + r * (gt[c] + bth[c]));
    float v = z * ht + (1.0f - z) * hp[c];
    hn[c] = v;
    hnb[c] = (bf16)v;
  }
  *(f32x4*)(hf + hrow + j) = hn;
  *(bf16x4*)(hb + hrow + j) = hnb;

  float* op = fwd
      ? (out + ((long)b * TDIM + (TDIM - 1 - s)) * (2 * HDIM) + j)
      : (out + ((long)b * TDIM + s) * (2 * HDIM) + HDIM + j);
  *(f32x4*)op = hn;
}

extern "C" void kernel_launch(void* const* d_in, const int* in_sizes, int n_in,
                              void* d_out, int out_size, void* d_ws, size_t ws_size,
                              hipStream_t stream) {
  const float* x     = (const float*)d_in[0];   // [B,T,I]
  const float* h0    = (const float*)d_in[1];   // [B,H]
  const float* bih0  = (const float*)d_in[2];   // [B,H]
  const float* W_izr = (const float*)d_in[3];   // [2H,I]
  const float* b_izr = (const float*)d_in[4];   // [2H]
  const float* W_hzr = (const float*)d_in[5];   // [2H,H]
  const float* b_hzr = (const float*)d_in[6];   // [2H]
  const float* W_it  = (const float*)d_in[7];   // [H,I]
  const float* b_it  = (const float*)d_in[8];   // [H]
  const float* W_ht  = (const float*)d_in[9];   // [H,H]
  const float* b_ht  = (const float*)d_in[10];  // [H]
  float* out = (float*)d_out;                   // [B,T,2H]

  const long n_x  = (long)BDIM * TDIM * IDIM;       // 67,108,864
  const long n_U  = (long)BDIM * TDIM * 3 * HDIM;   // 201,326,592
  const long n_Wi = (long)3 * HDIM * IDIM;          // 3,145,728
  const long n_Wh = (long)3 * HDIM * HDIM;          // 3,145,728
  const long n_h  = (long)2 * BDIM * HDIM;          // 8,388,608
  const long n_Gh = (long)2 * BDIM * 3 * HDIM;      // 25,165,824

  bf16* x_bf = (bf16*)d_ws;
  bf16* U    = x_bf + n_x;
  bf16* Wi   = U + n_U;
  bf16* Wh   = Wi + n_Wi;
  bf16* h_bf = Wh + n_Wh;
  float* Gh  = (float*)(h_bf + n_h);   // byte offset even & /4: all counts even
  float* h_f = Gh + n_Gh;
  // total ws use: 2*(n_x+n_U+n_Wi+n_Wh+n_h) + 4*(n_Gh+n_h) = 700,448,768 B

  // --- phase 0: conversions ---
  conv_bf16<<<(unsigned)(n_x / 4 / 256), 256, 0, stream>>>(x, x_bf, n_x / 4);
  conv_bf16<<<(unsigned)(2 * HDIM * IDIM / 4 / 256), 256, 0, stream>>>(
      W_izr, Wi, 2L * HDIM * IDIM / 4);
  conv_bf16<<<(unsigned)(HDIM * IDIM / 4 / 256), 256, 0, stream>>>(
      W_it, Wi + 2L * HDIM * IDIM, (long)HDIM * IDIM / 4);
  conv_bf16<<<(unsigned)(2 * HDIM * HDIM / 4 / 256), 256, 0, stream>>>(
      W_hzr, Wh, 2L * HDIM * HDIM / 4);
  conv_bf16<<<(unsigned)(HDIM * HDIM / 4 / 256), 256, 0, stream>>>(
      W_ht, Wh + 2L * HDIM * HDIM, (long)HDIM * HDIM / 4);
  init_h<<<(unsigned)(n_h / 4 / 256), 256, 0, stream>>>(h0, bih0, h_f, h_bf);

  // --- phase 1: input projections U = X @ Wi^T  (M=65536, N=3072, K=1024) ---
  {
    dim3 g(3 * HDIM / 128, BDIM * TDIM / 128);   // (24, 512)
    gemm_bt<bf16><<<g, 256, 0, stream>>>(x_bf, Wi, U,
                                         BDIM * TDIM, 3 * HDIM, IDIM);
  }

  // --- phase 2: 16 recurrent steps, fwd+bwd stacked (M=8192) ---
  dim3 gs(3 * HDIM / 128, 2 * BDIM / 128);       // (24, 64)
  for (int s = 0; s < TDIM; ++s) {
    gemm_bt<float><<<gs, 256, 0, stream>>>(h_bf, Wh, Gh,
                                           2 * BDIM, 3 * HDIM, HDIM);
    gate_step<<<2 * BDIM, 256, 0, stream>>>(U, Gh, h_f, h_bf,
                                            b_izr, b_hzr, b_it, b_ht, out, s);
  }
}